// Round 3
// baseline (73.139 us; speedup 1.0000x reference)
//
#include <hip/hip_runtime.h>

// MPO/TT embedding, single fused kernel. out[t] = A2[h] (16x64) . B3[l] (64x48)
// cores: c0 (1,8,4,32) c1 (32,8,4,64) c2 (64,8,4,64) c3 (64,8,4,24) c4 (24,8,3,1)
// v = token id; h = v>>9 (i1=h>>3,i2=h&7); l = v&511 (i3=l>>6, l2=l&63, i4=l2>>3, i5=l2&7)
// o = o12*48 + o345 ; o12 = o1*4+o2 (16) ; o345 = o3*12+o4*3+o5 (48), jj = o345/3 (16)
//
// Block b handles l == b (512 blocks). All intermediates live in LDS:
//   B4s[r3][o45]   = sum_r4 c3[r3,i4,o4,r4] * c4[r4,i5,o5]
//   B3s[r2][jj][4] = sum_r3 c2[r2,i3,o3,r3] * B4s[r3][o45]   (padded float4 groups)
//   per token: A2s[o12][r2] = sum_r1 c0[i1,o1,r1] * c1[r1,i2,o2,r2]
//              out = sum_r2 A2s * B3s
__global__ __launch_bounds__(256) void k_fused(const int* __restrict__ ids,
                                               const float* __restrict__ c0,
                                               const float* __restrict__ c1,
                                               const float* __restrict__ c2,
                                               const float* __restrict__ c3,
                                               const float* __restrict__ c4,
                                               float* __restrict__ out,
                                               int n_tokens) {
    const int l  = blockIdx.x;           // 0..511
    const int t  = threadIdx.x;          // 256
    const int i3 = l >> 6, l2 = l & 63;
    const int i4 = l2 >> 3, i5 = l2 & 7;

    __shared__ float c0s[1024];          // full c0 copy (4 KB)
    __shared__ float c4s[576];           // full c4 copy (2.25 KB)
    __shared__ float B4s[64 * 12];       // 3 KB
    __shared__ float B3s[64 * 16 * 4];   // 16 KB, [r2][jj][{3 vals,pad}]
    __shared__ float A2s[16 * 68];       // 4.25 KB, row-padded to 68 (bank spread)
    __shared__ int   s_list[4096];       // worst-case token list (16 KB)
    __shared__ int   s_cnt;

    if (t == 0) s_cnt = 0;
    __syncthreads();

    // stage c0 / c4; scan & bucket ids (independent, one sync covers all)
    reinterpret_cast<float4*>(c0s)[t] = reinterpret_cast<const float4*>(c0)[t];
    if (t < 144) reinterpret_cast<float4*>(c4s)[t] = reinterpret_cast<const float4*>(c4)[t];
    for (int i = t; i < n_tokens; i += 256) {
        int v = ids[i];
        if ((v & 511) == l) {
            int p = atomicAdd(&s_cnt, 1);
            if (p < 4096) s_list[p] = (i << 6) | (v >> 9);   // pack token idx + h
        }
    }
    __syncthreads();

    // ---- B4s[r3][o45] : threads (r3 = t>>2, m = o4 = t&3) ----
    {
        int r3 = t >> 2, m = t & 3;
        const float* c3p = c3 + r3 * 768 + i4 * 96 + m * 24;  // [r3][i4][o4=m][r4]
        const float* c4r = c4s + i5 * 3;                      // [r4][i5][o5]
        float a0 = 0.f, a1 = 0.f, a2 = 0.f;
#pragma unroll
        for (int r4q = 0; r4q < 24; r4q += 4) {
            float4 cv = *reinterpret_cast<const float4*>(c3p + r4q);
            float cc[4] = {cv.x, cv.y, cv.z, cv.w};
#pragma unroll
            for (int d = 0; d < 4; ++d) {
                const float* b = c4r + (r4q + d) * 24;
                a0 += cc[d] * b[0];
                a1 += cc[d] * b[1];
                a2 += cc[d] * b[2];
            }
        }
        float* o = B4s + r3 * 12 + m * 3;
        o[0] = a0; o[1] = a1; o[2] = a2;
    }
    __syncthreads();

    // ---- B3s[r2][jj][4] : threads (r2 = t>>2, q = o3 = t&3) ----
    {
        int r2 = t >> 2, q = t & 3;
        const float* c2p = c2 + r2 * 2048 + i3 * 256 + q * 64;   // [r2][i3][o3=q][r3]
        const float4* b4p = reinterpret_cast<const float4*>(B4s);
        float acc[4][3] = {};
#pragma unroll 4
        for (int r3q = 0; r3q < 64; r3q += 4) {
            float4 cv = *reinterpret_cast<const float4*>(c2p + r3q);
            float cc[4] = {cv.x, cv.y, cv.z, cv.w};
#pragma unroll
            for (int d = 0; d < 4; ++d) {
                float4 b0 = b4p[(r3q + d) * 3 + 0];
                float4 b1 = b4p[(r3q + d) * 3 + 1];
                float4 b2 = b4p[(r3q + d) * 3 + 2];
                float a = cc[d];
                acc[0][0] += a * b0.x; acc[0][1] += a * b0.y; acc[0][2] += a * b0.z;
                acc[1][0] += a * b0.w; acc[1][1] += a * b1.x; acc[1][2] += a * b1.y;
                acc[2][0] += a * b1.z; acc[2][1] += a * b1.w; acc[2][2] += a * b2.x;
                acc[3][0] += a * b2.y; acc[3][1] += a * b2.z; acc[3][2] += a * b2.w;
            }
        }
        float4* o = reinterpret_cast<float4*>(B3s) + (r2 * 16 + q * 4);
#pragma unroll
        for (int g = 0; g < 4; ++g)
            o[g] = make_float4(acc[g][0], acc[g][1], acc[g][2], 0.f);
    }
    __syncthreads();

    // ---- per-token: A2 into LDS, then GEMM to out ----
    const int cnt = s_cnt;
    const int o12 = t >> 4, w = t & 15;     // w = jj = o345 group
    const int o1 = o12 >> 2, o2 = o12 & 3;
    const int rq = w * 4;                   // r2 quad this thread computes in A2s

    for (int k = 0; k < cnt; ++k) {
        int e = s_list[k];
        int token = e >> 6, h = e & 63;
        int i1 = h >> 3, i2 = h & 7;

        // A2s[o12][rq..rq+3] = sum_r1 c0[i1,o1,r1] * c1[r1,i2,o2,rq..rq+3]
        {
            const float* c1p = c1 + (i2 * 4 + o2) * 64 + rq;    // + r1*2048
            const float* c0r = c0s + i1 * 128 + o1 * 32;
            float sx = 0.f, sy = 0.f, sz = 0.f, sw = 0.f;
#pragma unroll
            for (int r1 = 0; r1 < 32; ++r1) {
                float a = c0r[r1];
                float4 cv = *reinterpret_cast<const float4*>(c1p + r1 * 2048);
                sx += a * cv.x; sy += a * cv.y; sz += a * cv.z; sw += a * cv.w;
            }
            *reinterpret_cast<float4*>(A2s + o12 * 68 + rq) = make_float4(sx, sy, sz, sw);
        }
        __syncthreads();

        // out[token][o12*48 + 3w + c] = sum_r2 A2s[o12][r2] * B3s[r2][w][c]
        {
            const float* arow = A2s + o12 * 68;
            const float4* b3 = reinterpret_cast<const float4*>(B3s) + w;
            float acc0 = 0.f, acc1 = 0.f, acc2 = 0.f;
#pragma unroll 4
            for (int r2q = 0; r2q < 64; r2q += 4) {
                float4 av = *reinterpret_cast<const float4*>(arow + r2q);
                float aa[4] = {av.x, av.y, av.z, av.w};
#pragma unroll
                for (int d = 0; d < 4; ++d) {
                    float4 bv = b3[(r2q + d) * 16];
                    acc0 += aa[d] * bv.x;
                    acc1 += aa[d] * bv.y;
                    acc2 += aa[d] * bv.z;
                }
            }
            float* o = out + (size_t)token * 768 + o12 * 48 + w * 3;
            o[0] = acc0; o[1] = acc1; o[2] = acc2;
        }
        __syncthreads();
    }
}

extern "C" void kernel_launch(void* const* d_in, const int* in_sizes, int n_in,
                              void* d_out, int out_size, void* d_ws, size_t ws_size,
                              hipStream_t stream) {
    const int*   ids = (const int*)d_in[0];
    const float* c0  = (const float*)d_in[1];
    const float* c1  = (const float*)d_in[2];
    const float* c2  = (const float*)d_in[3];
    const float* c3  = (const float*)d_in[4];
    const float* c4  = (const float*)d_in[5];
    float* out = (float*)d_out;

    int n_tokens = in_sizes[0];   // 8*512 = 4096

    k_fused<<<512, 256, 0, stream>>>(ids, c0, c1, c2, c3, c4, out, n_tokens);
}

// Round 4
// 40.265 us; speedup vs baseline: 1.8164x; 1.8164x over previous
//
#include <hip/hip_runtime.h>

// MPO/TT embedding: out[t] = A2[h(t)] (16x64) . B3[l(t)] (64x48)
// cores: c0 (1,8,4,32) c1 (32,8,4,64) c2 (64,8,4,64) c3 (64,8,4,24) c4 (24,8,3,1)
// v = token id; h = v>>9 (i1=h>>3,i2=h&7); l = v&511 (i3=l>>6, l2=l&63, i4=l2>>3, i5=l2&7)
// o = o12*48 + o345 ; o12 = o1*4+o2 (16) ; o345 = o3*12+o4*3+o5 (48); jj = o345/3 (16)

// Prep kernel:
//   blocks 0..2047  : (l = b>>2, p = b&3) -> B3p[l][r2 in 16p..16p+15][jj][4]
//                     B4[l2] (64x12) recomputed per block in LDS (cheap: 72 FMA/thr)
//   blocks 2048..2111: A2T[h][r2][o12] (256 KB)
__global__ __launch_bounds__(256) void k_prep(const float* __restrict__ c0,
                                              const float* __restrict__ c1,
                                              const float* __restrict__ c2,
                                              const float* __restrict__ c3,
                                              const float* __restrict__ c4,
                                              float* __restrict__ A2T,
                                              float* __restrict__ B3p) {
    const int t = threadIdx.x;
    const int b = blockIdx.x;

    if (b >= 2048) {
        // ---- A2T: h = b-2048 ----
        int h = b - 2048;
        int r2 = t >> 2, o1 = t & 3;
        int i1 = h >> 3, i2 = h & 7;
        const float* c0p = c0 + i1 * 128 + o1 * 32;   // [i1][o1][r1]
        const float* c1p = c1 + i2 * 256 + r2;        // + r1*2048 + o2*64
        float a0 = 0.f, a1 = 0.f, a2 = 0.f, a3 = 0.f;
#pragma unroll
        for (int r1 = 0; r1 < 32; ++r1) {
            float a = c0p[r1];
            const float* p = c1p + r1 * 2048;
            a0 += a * p[0];
            a1 += a * p[64];
            a2 += a * p[128];
            a3 += a * p[192];
        }
        reinterpret_cast<float4*>(A2T)[(h * 64 + r2) * 4 + o1] =
            make_float4(a0, a1, a2, a3);
        return;
    }

    // ---- B3p quarter: l = b>>2, r2 in [16p, 16p+16) ----
    const int l = b >> 2, p = b & 3;
    const int i3 = l >> 6, l2 = l & 63;
    const int i4 = l2 >> 3, i5 = l2 & 7;

    __shared__ float B4s[64 * 12];   // [r3][o45]
    {
        int r3 = t >> 2, m = t & 3;  // m = o4
        const float* c3p = c3 + r3 * 768 + i4 * 96 + m * 24;  // [r3][i4][o4=m][r4], 16B-aligned
        const float* c4p = c4 + i5 * 3;                       // [r4][i5][o5]
        float a0 = 0.f, a1 = 0.f, a2 = 0.f;
#pragma unroll
        for (int r4q = 0; r4q < 24; r4q += 4) {
            float4 cv = *reinterpret_cast<const float4*>(c3p + r4q);
            float cc[4] = {cv.x, cv.y, cv.z, cv.w};
#pragma unroll
            for (int d = 0; d < 4; ++d) {
                const float* bb = c4p + (r4q + d) * 24;
                a0 += cc[d] * bb[0];
                a1 += cc[d] * bb[1];
                a2 += cc[d] * bb[2];
            }
        }
        float* o = B4s + r3 * 12 + m * 3;
        o[0] = a0; o[1] = a1; o[2] = a2;
    }
    __syncthreads();

    {
        int r2 = 16 * p + (t >> 4);
        int jj = t & 15;
        int o3 = jj >> 2, g = jj & 3;    // o45 = 3g + c
        const float* c2p = c2 + r2 * 2048 + i3 * 256 + o3 * 64;  // + r3
        float a0 = 0.f, a1 = 0.f, a2 = 0.f;
#pragma unroll
        for (int r3q = 0; r3q < 64; r3q += 4) {
            float4 cv = *reinterpret_cast<const float4*>(c2p + r3q);
            float cc[4] = {cv.x, cv.y, cv.z, cv.w};
#pragma unroll
            for (int d = 0; d < 4; ++d) {
                const float* bb = B4s + (r3q + d) * 12 + 3 * g;
                a0 += cc[d] * bb[0];
                a1 += cc[d] * bb[1];
                a2 += cc[d] * bb[2];
            }
        }
        reinterpret_cast<float4*>(B3p)[(l * 64 + r2) * 16 + jj] =
            make_float4(a0, a1, a2, 0.f);
    }
}

// main: one wave per token; lane = (q = o12 quad)*16 + jj (o345 group)
__global__ __launch_bounds__(256) void k_main(const int* __restrict__ ids,
                                              const float* __restrict__ A2T,
                                              const float* __restrict__ B3p,
                                              float* __restrict__ out,
                                              int n_tokens) {
    int t = threadIdx.x;
    int wave = t >> 6, lane = t & 63;
    int token = blockIdx.x * 4 + wave;
    if (token >= n_tokens) return;
    int q = lane >> 4, jj = lane & 15;
    int v = ids[token];
    int h = v >> 9, l = v & 511;
    const float4* A = reinterpret_cast<const float4*>(A2T) + h * 256 + q;   // [(h*64+r2)*4+q]
    const float4* B = reinterpret_cast<const float4*>(B3p) + l * 1024 + jj; // [(l*64+r2)*16+jj]
    float acc[4][3] = {};
#pragma unroll 16
    for (int r2 = 0; r2 < 64; ++r2) {
        float4 a = A[r2 * 4];
        float4 b = B[r2 * 16];
        acc[0][0] += a.x * b.x; acc[0][1] += a.x * b.y; acc[0][2] += a.x * b.z;
        acc[1][0] += a.y * b.x; acc[1][1] += a.y * b.y; acc[1][2] += a.y * b.z;
        acc[2][0] += a.z * b.x; acc[2][1] += a.z * b.y; acc[2][2] += a.z * b.z;
        acc[3][0] += a.w * b.x; acc[3][1] += a.w * b.y; acc[3][2] += a.w * b.z;
    }
    float* o = out + (size_t)token * 768 + 3 * jj;
#pragma unroll
    for (int qq = 0; qq < 4; ++qq) {
        int o12 = 4 * q + qq;
        o[o12 * 48 + 0] = acc[qq][0];
        o[o12 * 48 + 1] = acc[qq][1];
        o[o12 * 48 + 2] = acc[qq][2];
    }
}

extern "C" void kernel_launch(void* const* d_in, const int* in_sizes, int n_in,
                              void* d_out, int out_size, void* d_ws, size_t ws_size,
                              hipStream_t stream) {
    const int*   ids = (const int*)d_in[0];
    const float* c0  = (const float*)d_in[1];
    const float* c1  = (const float*)d_in[2];
    const float* c2  = (const float*)d_in[3];
    const float* c3  = (const float*)d_in[4];
    const float* c4  = (const float*)d_in[5];
    float* out = (float*)d_out;

    char* ws = (char*)d_ws;
    float* A2T = (float*)(ws + 0);          // 262144 B
    float* B3p = (float*)(ws + 262144);     // 8388608 B (total ~8.6 MB)

    int n_tokens = in_sizes[0];             // 8*512 = 4096

    k_prep<<<2112, 256, 0, stream>>>(c0, c1, c2, c3, c4, A2T, B3p);
    k_main<<<(n_tokens + 3) / 4, 256, 0, stream>>>(ids, A2T, B3p, out, n_tokens);
}

// Round 5
// 39.217 us; speedup vs baseline: 1.8650x; 1.0267x over previous
//
#include <hip/hip_runtime.h>

// MPO/TT embedding: out[t] = A2[h(t)] (16x64) . B3[l(t)] (64x48)
// cores: c0 (1,8,4,32) c1 (32,8,4,64) c2 (64,8,4,64) c3 (64,8,4,24) c4 (24,8,3,1)
// v = token id; h = v>>9 (i1=h>>3,i2=h&7); l = v&511 (i3=l>>6, l2=l&63, i4=l2>>3, i5=l2&7)
// o = o12*48 + o345 ; o12 = o1*4+o2 (16) ; o345 = o3*12+o4*3+o5 (48); jj = o345/3 (16)

// Prep kernel:
//   blocks 0..2047   : (l = b>>2, p = b&3) -> B3p[l][r2 in 16p..16p+15][jj][4]
//                      B4[l2] (64x12) recomputed per block in LDS
//   blocks 2048..2111: A2T[h][r2][o12] (256 KB)
__global__ __launch_bounds__(256) void k_prep(const float* __restrict__ c0,
                                              const float* __restrict__ c1,
                                              const float* __restrict__ c2,
                                              const float* __restrict__ c3,
                                              const float* __restrict__ c4,
                                              float* __restrict__ A2T,
                                              float* __restrict__ B3p) {
    const int t = threadIdx.x;
    const int b = blockIdx.x;

    if (b >= 2048) {
        // ---- A2T: h = b-2048 ----
        int h = b - 2048;
        int r2 = t >> 2, o1 = t & 3;
        int i1 = h >> 3, i2 = h & 7;
        const float* c0p = c0 + i1 * 128 + o1 * 32;   // [i1][o1][r1]
        const float* c1p = c1 + i2 * 256 + r2;        // + r1*2048 + o2*64
        float a0 = 0.f, a1 = 0.f, a2 = 0.f, a3 = 0.f;
#pragma unroll
        for (int r1 = 0; r1 < 32; ++r1) {
            float a = c0p[r1];
            const float* p = c1p + r1 * 2048;
            a0 += a * p[0];
            a1 += a * p[64];
            a2 += a * p[128];
            a3 += a * p[192];
        }
        reinterpret_cast<float4*>(A2T)[(h * 64 + r2) * 4 + o1] =
            make_float4(a0, a1, a2, a3);
        return;
    }

    // ---- B3p quarter: l = b>>2, r2 in [16p, 16p+16) ----
    const int l = b >> 2, p = b & 3;
    const int i3 = l >> 6, l2 = l & 63;
    const int i4 = l2 >> 3, i5 = l2 & 7;

    __shared__ float B4s[64 * 12];   // [r3][o45]
    {
        int r3 = t >> 2, m = t & 3;  // m = o4
        const float* c3p = c3 + r3 * 768 + i4 * 96 + m * 24;  // [r3][i4][o4=m][r4]
        const float* c4p = c4 + i5 * 3;                       // [r4][i5][o5]
        float a0 = 0.f, a1 = 0.f, a2 = 0.f;
#pragma unroll
        for (int r4q = 0; r4q < 24; r4q += 4) {
            float4 cv = *reinterpret_cast<const float4*>(c3p + r4q);
            float cc[4] = {cv.x, cv.y, cv.z, cv.w};
#pragma unroll
            for (int d = 0; d < 4; ++d) {
                const float* bb = c4p + (r4q + d) * 24;
                a0 += cc[d] * bb[0];
                a1 += cc[d] * bb[1];
                a2 += cc[d] * bb[2];
            }
        }
        float* o = B4s + r3 * 12 + m * 3;
        o[0] = a0; o[1] = a1; o[2] = a2;
    }
    __syncthreads();

    {
        int r2 = 16 * p + (t >> 4);
        int jj = t & 15;
        int o3 = jj >> 2, g = jj & 3;    // o45 = 3g + c
        const float* c2p = c2 + r2 * 2048 + i3 * 256 + o3 * 64;  // + r3
        float a0 = 0.f, a1 = 0.f, a2 = 0.f;
#pragma unroll
        for (int r3q = 0; r3q < 64; r3q += 4) {
            float4 cv = *reinterpret_cast<const float4*>(c2p + r3q);
            float cc[4] = {cv.x, cv.y, cv.z, cv.w};
#pragma unroll
            for (int d = 0; d < 4; ++d) {
                const float* bb = B4s + (r3q + d) * 12 + 3 * g;
                a0 += cc[d] * bb[0];
                a1 += cc[d] * bb[1];
                a2 += cc[d] * bb[2];
            }
        }
        reinterpret_cast<float4*>(B3p)[(l * 64 + r2) * 16 + jj] =
            make_float4(a0, a1, a2, 0.f);
    }
}

// main: one BLOCK per token. 4 waves split the r2 loop (16 each) for 4x TLP;
// partials summed in LDS; coalesced float4 epilogue.
// thread t: rp = t>>6 (r2 quarter), q = (t>>4)&3 (o12 quad), jj = t&15 (o345 group)
__global__ __launch_bounds__(256) void k_main(const int* __restrict__ ids,
                                              const float* __restrict__ A2T,
                                              const float* __restrict__ B3p,
                                              float* __restrict__ out) {
    __shared__ float s[4 * 784];           // [rp][768 + 16 pad]
    const int token = blockIdx.x;
    const int t = threadIdx.x;
    const int rp = t >> 6;
    const int lane = t & 63;
    const int q = lane >> 4, jj = lane & 15;

    const int v = ids[token];              // block-uniform -> scalar load
    const int h = v >> 9, l = v & 511;

    const float4* A = reinterpret_cast<const float4*>(A2T) + h * 256 + rp * 64 + q;
    const float4* B = reinterpret_cast<const float4*>(B3p) + l * 1024 + rp * 256 + jj;

    float acc[4][3] = {};
#pragma unroll
    for (int r = 0; r < 16; ++r) {
        float4 a = A[r * 4];
        float4 b = B[r * 16];
        acc[0][0] += a.x * b.x; acc[0][1] += a.x * b.y; acc[0][2] += a.x * b.z;
        acc[1][0] += a.y * b.x; acc[1][1] += a.y * b.y; acc[1][2] += a.y * b.z;
        acc[2][0] += a.z * b.x; acc[2][1] += a.z * b.y; acc[2][2] += a.z * b.z;
        acc[3][0] += a.w * b.x; acc[3][1] += a.w * b.y; acc[3][2] += a.w * b.z;
    }

    // partials: s[rp][ (4q+qq)*48 + 3jj + c ]
    float* sp = s + rp * 784 + q * 192 + jj * 3;
#pragma unroll
    for (int qq = 0; qq < 4; ++qq) {
        sp[qq * 48 + 0] = acc[qq][0];
        sp[qq * 48 + 1] = acc[qq][1];
        sp[qq * 48 + 2] = acc[qq][2];
    }
    __syncthreads();

    // reduce 4 partials and store one float4 per thread (192 threads -> 768 floats)
    if (t < 192) {
        const float4* s4 = reinterpret_cast<const float4*>(s);      // 784/4 = 196 f4/plane
        float4 v0 = s4[t];
        float4 v1 = s4[196 + t];
        float4 v2 = s4[392 + t];
        float4 v3 = s4[588 + t];
        float4 r;
        r.x = (v0.x + v1.x) + (v2.x + v3.x);
        r.y = (v0.y + v1.y) + (v2.y + v3.y);
        r.z = (v0.z + v1.z) + (v2.z + v3.z);
        r.w = (v0.w + v1.w) + (v2.w + v3.w);
        reinterpret_cast<float4*>(out + (size_t)token * 768)[t] = r;
    }
}

extern "C" void kernel_launch(void* const* d_in, const int* in_sizes, int n_in,
                              void* d_out, int out_size, void* d_ws, size_t ws_size,
                              hipStream_t stream) {
    const int*   ids = (const int*)d_in[0];
    const float* c0  = (const float*)d_in[1];
    const float* c1  = (const float*)d_in[2];
    const float* c2  = (const float*)d_in[3];
    const float* c3  = (const float*)d_in[4];
    const float* c4  = (const float*)d_in[5];
    float* out = (float*)d_out;

    char* ws = (char*)d_ws;
    float* A2T = (float*)(ws + 0);          // 262144 B
    float* B3p = (float*)(ws + 262144);     // 8388608 B (total ~8.6 MB)

    int n_tokens = in_sizes[0];             // 8*512 = 4096

    k_prep<<<2112, 256, 0, stream>>>(c0, c1, c2, c3, c4, A2T, B3p);
    k_main<<<n_tokens, 256, 0, stream>>>(ids, A2T, B3p, out);
}